// Round 1
// baseline (12816.704 us; speedup 1.0000x reference)
//
#include <hip/hip_runtime.h>
#include <math.h>

// ESN reservoir, persistent kernel, round 19: tag-validated h exchange +
// XCD-local (intra-L2) communication with probed uniform fallback.
//
// r16/r18 step chain: store strips -> s_waitcnt(0) -> flag store -> [MALL]
// -> wave-0 flag poll -> [MALL] -> global_load_lds h -> compute.
// Counters: VALUBusy 20%, HBM 0.6% => ~80% of the 3.72us step is
// coherence-point latency (3 serial MALL hops), not work.
//
// This round:
//  - every exchanged h dword = 2x int8 payload + 16-bit tag (= step).
//    A dword store is atomic, so tag match certifies payload: visibility of
//    data IS the flag. One tagged load does gate + transfer. No producer
//    drain, no flag, no staged load.
//  - blocks read HW_REG_XCC_ID (hwreg 20), claim (xcd,slot) via device-scope
//    atomics; groups form per-XCD so the exchange coherence point is the
//    XCD-shared L2 (sc0-only, ~300cy) instead of the MALL (sc0+sc1, ~900cy).
//    A startup probe verifies intra-L2 visibility; uneven occupancy / probe
//    failure / barrier timeout -> UNIFORM fallback to device-scope policy.
//  - bounded spins + block-local dead-latch: worst case wrong, never a hang.
//  - buffer-reuse safety: same 2-step induction as the flag scheme (a block
//    reaches step t+1 only after all group members published t+1, which
//    requires each to have consumed tag t first).

#define RDIM   2048
#define BATCH  16
#define TSTEPS 2048
#define NIN    3
#define NOUT   3
#define NBLK   256
#define NTHR   512

typedef unsigned u32x4 __attribute__((ext_vector_type(4)));

// workspace layout (dwords)
#define HT0_DW     0            // [8 groups][2 batches][1024] tagged h dwords
#define HT1_DW     16384
#define DISC_DW    32768        // 8 per-XCD claim counters
#define ABAR_DW    32776
#define ABAR2_DW   32777
#define FAIL_DW    32778
#define PROBE_DW   32784        // 256 probe dwords
#define WS_USED_DW 33040

#define SPIN_MAX   (1L << 22)
#define POLL_MAX   (1L << 17)
#define PROBE_MAX  (1L << 14)

__device__ __forceinline__ unsigned sysld(const unsigned* p) {
    return __hip_atomic_load(p, __ATOMIC_RELAXED, __HIP_MEMORY_SCOPE_SYSTEM);
}

// fast: sc0 only -> L1 bypass, served/ordered at the XCD-shared L2.
// slow: sc0+sc1 -> device/system coherence point (MALL).
__device__ __forceinline__ void ld4_pol(u32x4& d, const unsigned* p, bool fastp) {
    if (fastp)
        asm volatile("global_load_dwordx4 %0, %1, off sc0\n\ts_waitcnt vmcnt(0)"
                     : "=v"(d) : "v"(p) : "memory");
    else
        asm volatile("global_load_dwordx4 %0, %1, off sc0 sc1\n\ts_waitcnt vmcnt(0)"
                     : "=v"(d) : "v"(p) : "memory");
}
__device__ __forceinline__ void ld1_fast(unsigned& d, const unsigned* p) {
    asm volatile("global_load_dword %0, %1, off sc0\n\ts_waitcnt vmcnt(0)"
                 : "=v"(d) : "v"(p) : "memory");
}
__device__ __forceinline__ void st1_pol(unsigned* p, unsigned v, bool fastp) {
    if (fastp)
        asm volatile("global_store_dword %0, %1, off sc0" :: "v"(p), "v"(v) : "memory");
    else
        asm volatile("global_store_dword %0, %1, off sc0 sc1" :: "v"(p), "v"(v) : "memory");
}

__device__ __forceinline__ int q8(float v) {          // round, clamp [-127,127]
    float c = fminf(127.f, fmaxf(-127.f, v));
    return (int)__builtin_rintf(c);
}
__device__ __forceinline__ unsigned pack4(int a, int b, int c, int d) {
    return (a & 0xff) | ((b & 0xff) << 8) | ((c & 0xff) << 16) | ((d & 0xff) << 24);
}
__device__ __forceinline__ int dot4i(unsigned a, unsigned b, int c) {
#if __has_builtin(__builtin_amdgcn_sdot4)
    return __builtin_amdgcn_sdot4((int)a, (int)b, c, false);
#else
    c += (int)(signed char)(a) * (int)(signed char)(b);
    c += (int)(signed char)(a >> 8)  * (int)(signed char)(b >> 8);
    c += (int)(signed char)(a >> 16) * (int)(signed char)(b >> 16);
    c += (int)(signed char)(a >> 24) * (int)(signed char)(b >> 24);
    return c;
#endif
}
__device__ __forceinline__ int dot16(uint4 wq, uint4 hq, int c) {
    c = dot4i(wq.x, hq.x, c);
    c = dot4i(wq.y, hq.y, c);
    c = dot4i(wq.z, hq.z, c);
    c = dot4i(wq.w, hq.w, c);
    return c;
}

extern "C" __global__ void __launch_bounds__(NTHR, 1) esn_persist(
    const float* __restrict__ W,       // [R,R] fp32
    const float* __restrict__ Win,     // [R,3]
    const float* __restrict__ x,       // [B,T,3]
    const float* __restrict__ Wout,    // [3,R]
    const float* __restrict__ bout,    // [3]
    unsigned* wsu,                     // workspace (dwords, see layout)
    float* __restrict__ out)           // [B,T,3]
{
    __shared__ __align__(16) unsigned hs_dw[1024]; // 4 KB: detagged h int8 [2][2048]
    __shared__ int  red[8][544];                   // transpose-reduce (int partials)
    __shared__ float wscale[64];                   // per-row W scale (m/127)
    __shared__ int s_map[3];                       // g, rg, policy
    extern __shared__ unsigned wlds[];             // 128 KB: W int8 [64 rows][512 dw]

    const int tid  = threadIdx.x;
    const int lane = tid & 63;
    const int w    = tid >> 6;                     // wave 0..7
    const int blk  = blockIdx.x;

    // ---- discovery: dynamic (XCD, slot) mapping ----
    if (tid == 0) {
        unsigned xcc;
        asm volatile("s_getreg_b32 %0, hwreg(20, 0, 32)" : "=s"(xcc)); // HW_REG_XCC_ID
        xcc &= 7u;
        unsigned slot = atomicAdd(&wsu[DISC_DW + xcc], 1u);
        __builtin_amdgcn_s_waitcnt(0);             // disc add globally performed first
        atomicAdd(&wsu[ABAR_DW], 1u);
        long sp = 0;
        while (sysld(&wsu[ABAR_DW]) < NBLK && ++sp < SPIN_MAX)
            __builtin_amdgcn_s_sleep(8);
        bool bar_ok = sysld(&wsu[ABAR_DW]) >= NBLK;
        bool uni = bar_ok && slot < 32u;
        if (uni)
            for (int i = 0; i < 8; ++i)
                if (sysld(&wsu[DISC_DW + i]) != 32u) uni = false;
        s_map[0] = uni ? (int)xcc  : (blk >> 5);
        s_map[1] = uni ? (int)slot : (blk & 31);
        s_map[2] = uni ? 1 : 0;
    }
    __syncthreads();
    const int g  = s_map[0];                       // batches g*2..+2
    const int rg = s_map[1];                       // rows rg*64..+64
    const bool try_fast = s_map[2] != 0;

    // ---- probe: verify intra-group sc0-only visibility (fast mode gate) ----
    if (try_fast) {
        if (tid == 0) st1_pol(&wsu[PROBE_DW + g * 32 + rg], 0xC0DEu, true);
        if (w == 0) {
            long r = 0; bool got = false;
            for (;;) {
                unsigned v = 0xC0DEu;
                if (lane < 32) ld1_fast(v, &wsu[PROBE_DW + g * 32 + lane]);
                if (__all((int)(v == 0xC0DEu))) { got = true; break; }
                if (++r > PROBE_MAX) break;
                __builtin_amdgcn_s_sleep(1);
            }
            if (tid == 0 && !got) atomicAdd(&wsu[FAIL_DW], 1u);
        }
    }
    __syncthreads();
    if (tid == 0) {
        __builtin_amdgcn_s_waitcnt(0);             // fail add performed before abar2
        atomicAdd(&wsu[ABAR2_DW], 1u);
        long sp = 0;
        while (sysld(&wsu[ABAR2_DW]) < NBLK && ++sp < SPIN_MAX)
            __builtin_amdgcn_s_sleep(8);
        s_map[2] = (try_fast && sysld(&wsu[FAIL_DW]) == 0u &&
                    sysld(&wsu[ABAR2_DW]) >= NBLK) ? 1 : 0;
    }
    __syncthreads();
    const bool fastp = s_map[2] != 0;              // uniform across ALL blocks

    const int rbase = rg * 64 + w * 8;             // wave's 8 rows
    const int b0    = g * 2;

    // ---- one-time: quantize W rows -> LDS int8 (per-row scale) ----
#pragma unroll
    for (int rr = 0; rr < 8; ++rr) {
        const int   row = rbase + rr;
        const float4* Wr = (const float4*)(W + (size_t)row * RDIM);
        float m = 0.f;
#pragma unroll
        for (int j = 0; j < 8; ++j) {              // lane covers 8 float4 = 32 elems
            float4 v = Wr[j * 64 + lane];
            m = fmaxf(m, fmaxf(fmaxf(fabsf(v.x), fabsf(v.y)),
                               fmaxf(fabsf(v.z), fabsf(v.w))));
        }
#pragma unroll
        for (int off = 32; off >= 1; off >>= 1)
            m = fmaxf(m, __shfl_xor(m, off, 64));
        const float inv = (m > 0.f) ? 127.f / m : 0.f;
        if (lane == 0) wscale[w * 8 + rr] = (m > 0.f) ? m / 127.f : 0.f;
#pragma unroll
        for (int j = 0; j < 8; ++j) {
            float4 v = Wr[j * 64 + lane];
            wlds[(w * 8 + rr) * 512 + j * 64 + lane] =
                pack4(q8(v.x * inv), q8(v.y * inv), q8(v.z * inv), q8(v.w * inv));
        }
    }
    __syncthreads();

    unsigned* const ht0 = wsu + HT0_DW;
    unsigned* const ht1 = wsu + HT1_DW;
    bool dead = false;

    for (int t = 0; t <= TSTEPS; ++t) {
        // ---- consume: one tagged load = gate + transfer (tags == t) ----
        // memset zeros give tag 0 + zero payload = valid h0 at t=0.
        u32x4 hd;
        {
            const unsigned* hp = ((t & 1) ? ht1 : ht0) + g * 2048 + tid * 4;
            const unsigned tg = (unsigned)t & 0xffffu;
            long r = 0;
            for (;;) {
                ld4_pol(hd, hp, fastp);
                int ok = (hd[0] >> 16) == tg && (hd[1] >> 16) == tg &&
                         (hd[2] >> 16) == tg && (hd[3] >> 16) == tg;
                int all8 = __syncthreads_and(ok);  // one barrier/round, uniform
                bool over = (r > POLL_MAX);
                if (all8 || dead || over) { dead = dead || over; break; }
                ++r;
                if (r > 256) __builtin_amdgcn_s_sleep(1);
            }
        }
        // detag -> stage into LDS, same layout as r16: int8 [2][2048]
        {
            unsigned lo = (hd[0] & 0xffffu) | (hd[1] << 16);
            unsigned hi = (hd[2] & 0xffffu) | (hd[3] << 16);
            ((uint2*)hs_dw)[tid] = make_uint2(lo, hi);
        }
        __syncthreads();                           // staging complete

        if (t < TSTEPS) {
            int acc[8][2];
#pragma unroll
            for (int r = 0; r < 8; ++r) { acc[r][0] = 0; acc[r][1] = 0; }

            // h granules: batch b0 at 0..127, b1 at 128..255 (16 k each)
            const uint4* h4 = (const uint4*)hs_dw;
            uint4 hA0 = h4[lane];            // b0, k = 16*lane..+16
            uint4 hA1 = h4[64 + lane];       // b0, k = 1024+16*lane..+16
            uint4 hB0 = h4[128 + lane];      // b1
            uint4 hB1 = h4[192 + lane];

            const uint4* w4p = (const uint4*)wlds;   // row r: 128 granules
#pragma unroll
            for (int rr = 0; rr < 8; ++rr) {
                const int wb = (w * 8 + rr) * 128;
                uint4 w0 = w4p[wb + lane];           // k = 16*lane..+16
                uint4 w1 = w4p[wb + 64 + lane];      // k = 1024+16*lane..+16
                acc[rr][0] = dot16(w0, hA0, acc[rr][0]);
                acc[rr][0] = dot16(w1, hA1, acc[rr][0]);
                acc[rr][1] = dot16(w0, hB0, acc[rr][1]);
                acc[rr][1] = dot16(w1, hB1, acc[rr][1]);
            }

            // ---- reduce: fold 32, swizzled transpose, sum 32 (int exact) ----
            int v[16];
#pragma unroll
            for (int i = 0; i < 16; ++i) {
                int a = acc[i >> 1][i & 1];
                v[i] = a + __shfl_xor(a, 32, 64);
            }
            if (lane < 32) {
#pragma unroll
                for (int i = 0; i < 16; ++i)
                    red[w][lane * 17 + ((i + lane) & 15)] = v[i];
            }
            __syncthreads();
            int qv = 0;
            if (lane < 16) {
                int s = 0;
#pragma unroll
                for (int l = 0; l < 32; ++l)
                    s += red[w][l * 17 + ((lane + l) & 15)];
                const int r_  = lane >> 1;          // 0..7
                const int b_  = lane & 1;
                const int row = rbase + r_;
                const int bg  = b0 + b_;
                // dequant: W ~ wq*s_r, h ~ hq/127
                float pre = (float)s * wscale[w * 8 + r_] * (1.f / 127.f);
#pragma unroll
                for (int c = 0; c < NIN; ++c)
                    pre += Win[row * NIN + c] * x[((size_t)bg * TSTEPS + t) * NIN + c];
                qv = q8(tanhf(pre) * 127.f);
            }
            // ---- produce: per-wave tagged stores (2 rows + tag16 per dword);
            // no drain, no flag — the tag self-validates at the consumer.
            const unsigned tg1 = (unsigned)(t + 1) & 0xffffu;
            const int p_ = lane & 3, bb = (lane >> 2) & 1;
            int qlo = __shfl(qv, 4 * p_ + bb,     64);   // row rbase+2p, batch bb
            int qhi = __shfl(qv, 4 * p_ + 2 + bb, 64);   // row rbase+2p+1
            if (lane < 8) {
                unsigned dv = (unsigned)(qlo & 0xff) |
                              ((unsigned)(qhi & 0xff) << 8) | (tg1 << 16);
                unsigned* dst = (((t + 1) & 1) ? ht1 : ht0) +
                                g * 2048 + bb * 1024 + rg * 32 + w * 4 + p_;
                st1_pol(dst, dv, fastp);
            }
        }

        // ---- projection of staged h (int8 in hs) by rotating block ----
        if (t > 0 && rg == ((t - 1) & 31)) {
            const signed char* hsv = (const signed char*)hs_dw;
            const int o = t - 1;
            if (w < 6) {
                const int b = w / NOUT;             // 0..1
                const int k = w % NOUT;             // 0..2
                float a = 0.f;
#pragma unroll
                for (int j = 0; j < 32; ++j) {
                    const int r = j * 64 + lane;
                    a += (float)hsv[b * RDIM + r] * Wout[k * RDIM + r];
                }
#pragma unroll
                for (int off = 32; off >= 1; off >>= 1)
                    a += __shfl_xor(a, off, 64);
                if (lane == 0)
                    out[((size_t)(b0 + b) * TSTEPS + o) * NOUT + k] =
                        a * (1.f / 127.f) + bout[k];
            }
        }
    }
}

extern "C" void kernel_launch(void* const* d_in, const int* in_sizes, int n_in,
                              void* d_out, int out_size, void* d_ws, size_t ws_size,
                              hipStream_t stream) {
    const float* x    = (const float*)d_in[0];
    const float* Win  = (const float*)d_in[1];
    const float* W    = (const float*)d_in[2];
    const float* Wout = (const float*)d_in[3];
    const float* bout = (const float*)d_in[4];
    float* out = (float*)d_out;
    unsigned* wsu = (unsigned*)d_ws;

    // zero tagged-h buffers (tag0 + zero payload = valid h0), discovery
    // counters, probes (~132 KB)
    hipMemsetAsync(d_ws, 0, (size_t)WS_USED_DW * sizeof(unsigned), stream);

    // allow 128 KB dynamic LDS (idempotent; same work every call)
    hipFuncSetAttribute((const void*)esn_persist,
                        hipFuncAttributeMaxDynamicSharedMemorySize, 131072);

    void* args[] = {(void*)&W, (void*)&Win, (void*)&x, (void*)&Wout, (void*)&bout,
                    (void*)&wsu, (void*)&out};
    hipError_t e = hipLaunchCooperativeKernel((const void*)esn_persist,
                                              dim3(NBLK), dim3(NTHR),
                                              args, 131072, stream);
    if (e != hipSuccess) {
        // Fallback: plain launch (256 blocks, 1/CU with ~150KB LDS -> all
        // co-resident; bounded spins guarantee no hang regardless).
        esn_persist<<<dim3(NBLK), dim3(NTHR), 131072, stream>>>(
            W, Win, x, Wout, bout, wsu, out);
    }
}

// Round 3
// 6760.690 us; speedup vs baseline: 1.8958x; 1.8958x over previous
//
#include <hip/hip_runtime.h>
#include <math.h>

// ESN reservoir, persistent kernel, round 21: tag-validated h exchange with
// per-lane independent polling + the missing end-of-step barrier.
//
// Post-mortem r20 (FAILED, absmax 0.91): removing the poll-round barrier
// also removed the only barrier between the rotating projection's hs_dw
// READS (end of iter t) and iter t+1's staging WRITES to hs_dw. Fast waves
// overwrote hs while projection waves were still reading it. r16 had this
// barrier in the flag gate; r19 had it in __syncthreads_and. Fix: ONE
// __syncthreads at end of loop body. Poll stays per-lane independent.
//
// Protocol (verified r19): every exchanged dword = 2x int8 payload +
// 16-bit tag (= step). Dword stores are atomic => tag certifies payload;
// visibility of data IS the flag. No producer drain, no flag word, no
// separate payload hop. Buffer reuse safe by 2-step induction: a block
// stores tag t+2 only after consuming tag t+1 from ALL group blocks, which
// requires each to have finished its tag-t loads (loads drained before
// their tag t+1 stores issue).
//
// Chain/step: compute(~1700cy) -> store issue -> MALL visible(~900)
// -> per-lane detect(~900) -> stage+barriers(~300) ~= 3800-4800cy vs 8900.

#define RDIM   2048
#define BATCH  16
#define TSTEPS 2048
#define NIN    3
#define NOUT   3
#define NBLK   256
#define NTHR   512

typedef unsigned u32x4 __attribute__((ext_vector_type(4)));

// workspace layout (dwords)
#define HT0_DW     0            // [8 groups][2 batches][1024] tagged h dwords
#define HT1_DW     16384
#define WS_USED_DW 32768

#define POLL_MAX   (1L << 16)

// UC (device coherence point) tagged-dword ops
__device__ __forceinline__ void ld4_uc(u32x4& d, const unsigned* p) {
    asm volatile("global_load_dwordx4 %0, %1, off sc0 sc1\n\ts_waitcnt vmcnt(0)"
                 : "=v"(d) : "v"(p) : "memory");
}
__device__ __forceinline__ void st1_uc(unsigned* p, unsigned v) {
    asm volatile("global_store_dword %0, %1, off sc0 sc1" :: "v"(p), "v"(v) : "memory");
}

__device__ __forceinline__ int q8(float v) {          // round, clamp [-127,127]
    float c = fminf(127.f, fmaxf(-127.f, v));
    return (int)__builtin_rintf(c);
}
__device__ __forceinline__ unsigned pack4(int a, int b, int c, int d) {
    return (a & 0xff) | ((b & 0xff) << 8) | ((c & 0xff) << 16) | ((d & 0xff) << 24);
}
__device__ __forceinline__ int dot4i(unsigned a, unsigned b, int c) {
#if __has_builtin(__builtin_amdgcn_sdot4)
    return __builtin_amdgcn_sdot4((int)a, (int)b, c, false);
#else
    c += (int)(signed char)(a) * (int)(signed char)(b);
    c += (int)(signed char)(a >> 8)  * (int)(signed char)(b >> 8);
    c += (int)(signed char)(a >> 16) * (int)(signed char)(b >> 16);
    c += (int)(signed char)(a >> 24) * (int)(signed char)(b >> 24);
    return c;
#endif
}
__device__ __forceinline__ int dot16(uint4 wq, uint4 hq, int c) {
    c = dot4i(wq.x, hq.x, c);
    c = dot4i(wq.y, hq.y, c);
    c = dot4i(wq.z, hq.z, c);
    c = dot4i(wq.w, hq.w, c);
    return c;
}

extern "C" __global__ void __launch_bounds__(NTHR, 1) esn_persist(
    const float* __restrict__ W,       // [R,R] fp32
    const float* __restrict__ Win,     // [R,3]
    const float* __restrict__ x,       // [B,T,3]
    const float* __restrict__ Wout,    // [3,R]
    const float* __restrict__ bout,    // [3]
    unsigned* wsu,                     // workspace (dwords, see layout)
    float* __restrict__ out)           // [B,T,3]
{
    __shared__ __align__(16) unsigned hs_dw[1024]; // 4 KB: detagged h int8 [2][2048]
    __shared__ int  red[8][544];                   // transpose-reduce (int partials)
    __shared__ float wscale[64];                   // per-row W scale (m/127)
    extern __shared__ unsigned wlds[];             // 128 KB: W int8 [64 rows][512 dw]

    const int tid  = threadIdx.x;
    const int lane = tid & 63;
    const int w    = tid >> 6;                     // wave 0..7
    const int blk  = blockIdx.x;
    const int rg   = blk & 31;                     // rows rg*64..+64
    const int g    = blk >> 5;                     // batches g*2..+2
    const int rbase = rg * 64 + w * 8;             // wave's 8 rows
    const int b0    = g * 2;

    // ---- one-time: quantize W rows -> LDS int8 (per-row scale) ----
#pragma unroll
    for (int rr = 0; rr < 8; ++rr) {
        const int   row = rbase + rr;
        const float4* Wr = (const float4*)(W + (size_t)row * RDIM);
        float m = 0.f;
#pragma unroll
        for (int j = 0; j < 8; ++j) {              // lane covers 8 float4 = 32 elems
            float4 v = Wr[j * 64 + lane];
            m = fmaxf(m, fmaxf(fmaxf(fabsf(v.x), fabsf(v.y)),
                               fmaxf(fabsf(v.z), fabsf(v.w))));
        }
#pragma unroll
        for (int off = 32; off >= 1; off >>= 1)
            m = fmaxf(m, __shfl_xor(m, off, 64));
        const float inv = (m > 0.f) ? 127.f / m : 0.f;
        if (lane == 0) wscale[w * 8 + rr] = (m > 0.f) ? m / 127.f : 0.f;
#pragma unroll
        for (int j = 0; j < 8; ++j) {
            float4 v = Wr[j * 64 + lane];
            wlds[(w * 8 + rr) * 512 + j * 64 + lane] =
                pack4(q8(v.x * inv), q8(v.y * inv), q8(v.z * inv), q8(v.w * inv));
        }
    }
    __syncthreads();

    unsigned* const ht0 = wsu + HT0_DW;
    unsigned* const ht1 = wsu + HT1_DW;

    for (int t = 0; t <= TSTEPS; ++t) {
        // ---- consume: per-lane tagged load = gate + transfer (tags == t) ----
        // memset zeros give tag 0 + zero payload = valid h0 at t=0.
        u32x4 hd;
        {
            const unsigned* hp = ((t & 1) ? ht1 : ht0) + g * 2048 + tid * 4;
            const unsigned tg = (unsigned)t & 0xffffu;
            long r = 0;
            for (;;) {
                ld4_uc(hd, hp);
                bool ok = (hd[0] >> 16) == tg && (hd[1] >> 16) == tg &&
                          (hd[2] >> 16) == tg && (hd[3] >> 16) == tg;
                if (ok || r > POLL_MAX) break;     // per-lane exit; never hangs
                ++r;
                if (r > 64) __builtin_amdgcn_s_sleep(1);
            }
        }
        // detag -> stage into LDS, layout int8 [2][2048] (as r16)
        {
            unsigned lo = (hd[0] & 0xffffu) | (hd[1] << 16);
            unsigned hi = (hd[2] & 0xffffu) | (hd[3] << 16);
            ((uint2*)hs_dw)[tid] = make_uint2(lo, hi);
        }
        __syncthreads();                           // staging complete

        if (t < TSTEPS) {
            int acc[8][2];
#pragma unroll
            for (int r = 0; r < 8; ++r) { acc[r][0] = 0; acc[r][1] = 0; }

            // h granules: batch b0 at 0..127, b1 at 128..255 (16 k each)
            const uint4* h4 = (const uint4*)hs_dw;
            uint4 hA0 = h4[lane];            // b0, k = 16*lane..+16
            uint4 hA1 = h4[64 + lane];       // b0, k = 1024+16*lane..+16
            uint4 hB0 = h4[128 + lane];      // b1
            uint4 hB1 = h4[192 + lane];

            const uint4* w4p = (const uint4*)wlds;   // row r: 128 granules
#pragma unroll
            for (int rr = 0; rr < 8; ++rr) {
                const int wb = (w * 8 + rr) * 128;
                uint4 w0 = w4p[wb + lane];           // k = 16*lane..+16
                uint4 w1 = w4p[wb + 64 + lane];      // k = 1024+16*lane..+16
                acc[rr][0] = dot16(w0, hA0, acc[rr][0]);
                acc[rr][0] = dot16(w1, hA1, acc[rr][0]);
                acc[rr][1] = dot16(w0, hB0, acc[rr][1]);
                acc[rr][1] = dot16(w1, hB1, acc[rr][1]);
            }

            // ---- reduce: fold 32, swizzled transpose, sum 32 (int exact) ----
            int v[16];
#pragma unroll
            for (int i = 0; i < 16; ++i) {
                int a = acc[i >> 1][i & 1];
                v[i] = a + __shfl_xor(a, 32, 64);
            }
            if (lane < 32) {
#pragma unroll
                for (int i = 0; i < 16; ++i)
                    red[w][lane * 17 + ((i + lane) & 15)] = v[i];
            }
            __syncthreads();
            int qv = 0;
            if (lane < 16) {
                int s = 0;
#pragma unroll
                for (int l = 0; l < 32; ++l)
                    s += red[w][l * 17 + ((lane + l) & 15)];
                const int r_  = lane >> 1;          // 0..7
                const int b_  = lane & 1;
                const int row = rbase + r_;
                const int bg  = b0 + b_;
                // dequant: W ~ wq*s_r, h ~ hq/127
                float pre = (float)s * wscale[w * 8 + r_] * (1.f / 127.f);
#pragma unroll
                for (int c = 0; c < NIN; ++c)
                    pre += Win[row * NIN + c] * x[((size_t)bg * TSTEPS + t) * NIN + c];
                qv = q8(tanhf(pre) * 127.f);
            }
            // ---- produce: per-wave tagged stores (2 rows + tag16 per dword);
            // no drain, no flag — each dword self-validates at the consumer.
            const unsigned tg1 = (unsigned)(t + 1) & 0xffffu;
            const int p_ = lane & 3, bb = (lane >> 2) & 1;
            int qlo = __shfl(qv, 4 * p_ + bb,     64);   // row rbase+2p, batch bb
            int qhi = __shfl(qv, 4 * p_ + 2 + bb, 64);   // row rbase+2p+1
            if (lane < 8) {
                unsigned dv = (unsigned)(qlo & 0xff) |
                              ((unsigned)(qhi & 0xff) << 8) | (tg1 << 16);
                unsigned* dst = (((t + 1) & 1) ? ht1 : ht0) +
                                g * 2048 + bb * 1024 + rg * 32 + w * 4 + p_;
                st1_uc(dst, dv);
            }
        }

        // ---- projection of staged h (int8 in hs) by rotating block ----
        if (t > 0 && rg == ((t - 1) & 31)) {
            const signed char* hsv = (const signed char*)hs_dw;
            const int o = t - 1;
            if (w < 6) {
                const int b = w / NOUT;             // 0..1
                const int k = w % NOUT;             // 0..2
                float a = 0.f;
#pragma unroll
                for (int j = 0; j < 32; ++j) {
                    const int r = j * 64 + lane;
                    a += (float)hsv[b * RDIM + r] * Wout[k * RDIM + r];
                }
#pragma unroll
                for (int off = 32; off >= 1; off >>= 1)
                    a += __shfl_xor(a, off, 64);
                if (lane == 0)
                    out[((size_t)(b0 + b) * TSTEPS + o) * NOUT + k] =
                        a * (1.f / 127.f) + bout[k];
            }
        }

        // ---- WAR fence: all hs_dw/red readers of step t done before any
        // thread's step t+1 staging write. (The barrier r20 lost — its
        // absence let fast pollers overwrite hs under the projection.)
        __syncthreads();
    }
}

extern "C" void kernel_launch(void* const* d_in, const int* in_sizes, int n_in,
                              void* d_out, int out_size, void* d_ws, size_t ws_size,
                              hipStream_t stream) {
    const float* x    = (const float*)d_in[0];
    const float* Win  = (const float*)d_in[1];
    const float* W    = (const float*)d_in[2];
    const float* Wout = (const float*)d_in[3];
    const float* bout = (const float*)d_in[4];
    float* out = (float*)d_out;
    unsigned* wsu = (unsigned*)d_ws;

    // zero tagged-h buffers (tag0 + zero payload = valid h0), ~128 KB
    hipMemsetAsync(d_ws, 0, (size_t)WS_USED_DW * sizeof(unsigned), stream);

    // allow 128 KB dynamic LDS (idempotent; same work every call)
    hipFuncSetAttribute((const void*)esn_persist,
                        hipFuncAttributeMaxDynamicSharedMemorySize, 131072);

    void* args[] = {(void*)&W, (void*)&Win, (void*)&x, (void*)&Wout, (void*)&bout,
                    (void*)&wsu, (void*)&out};
    hipError_t e = hipLaunchCooperativeKernel((const void*)esn_persist,
                                              dim3(NBLK), dim3(NTHR),
                                              args, 131072, stream);
    if (e != hipSuccess) {
        // Fallback: plain launch (256 blocks, 1/CU with ~150KB LDS -> all
        // co-resident; bounded spins guarantee no hang regardless).
        esn_persist<<<dim3(NBLK), dim3(NTHR), 131072, stream>>>(
            W, Win, x, Wout, bout, wsu, out);
    }
}